// Round 1
// baseline (829.025 us; speedup 1.0000x reference)
//
#include <hip/hip_runtime.h>
#include <hip/hip_bf16.h>

#define N_TOK 2048
#define DMODEL 2048
#define NH 16
#define DK 128
#define DFF 8192

typedef __attribute__((ext_vector_type(8))) short short8;
typedef __attribute__((ext_vector_type(4))) float f32x4;

__device__ __forceinline__ short f2bf(float f) {
    unsigned int x = __builtin_bit_cast(unsigned int, f);
    unsigned int r = (x + 0x7fffu + ((x >> 16) & 1u)) >> 16;
    return (short)r;
}

// ---------------- cast X (f32 -> bf16), 8 elems/thread ----------------
__global__ __launch_bounds__(256) void cast_f32_bf16(const float* __restrict__ in,
                                                     short* __restrict__ out, int n8) {
    int i = blockIdx.x * 256 + threadIdx.x;
    if (i >= n8) return;
    const float4* p = (const float4*)in + (size_t)i * 2;
    float4 a = p[0], b = p[1];
    short8 o;
    o[0] = f2bf(a.x); o[1] = f2bf(a.y); o[2] = f2bf(a.z); o[3] = f2bf(a.w);
    o[4] = f2bf(b.x); o[5] = f2bf(b.y); o[6] = f2bf(b.z); o[7] = f2bf(b.w);
    *(short8*)(out + (size_t)i * 8) = o;
}

// ---------------- transpose + cast to bf16 (64x64 LDS tiles) ----------------
// in: [R][C] (TIN), out: [C][R] (bf16). Batched via z.
template <typename TIN>
__global__ __launch_bounds__(256) void transpose_cast(const TIN* __restrict__ in,
                                                      short* __restrict__ out,
                                                      int R, int C, long sIn, long sOut) {
    __shared__ float t[64][65];
    in  += (long)blockIdx.z * sIn;
    out += (long)blockIdx.z * sOut;
    int tx = threadIdx.x & 63, ty = threadIdx.x >> 6;
    long r0 = (long)blockIdx.y * 64, c0 = (long)blockIdx.x * 64;
    for (int i = 0; i < 16; i++) {
        int r = ty + i * 4;
        t[r][tx] = (float)in[(r0 + r) * (long)C + c0 + tx];
    }
    __syncthreads();
    for (int i = 0; i < 16; i++) {
        int r = ty + i * 4;
        out[(c0 + r) * (long)R + r0 + tx] = f2bf(t[tx][r]);
    }
}

// ---------------- async global->LDS helper ----------------
__device__ __forceinline__ void gld_lds16(const short* g, short* l) {
    __builtin_amdgcn_global_load_lds(
        (const __attribute__((address_space(1))) void*)g,
        (__attribute__((address_space(3))) void*)l, 16, 0, 0);
}

// ---------------- bf16 GEMM, B pre-transposed ([n][k]) -------------------
// 128x128 tile, 4 waves (2x2 of 64x64), BK=32, m97 structure.
// MODE 0: out bf16, +bias            (QKV)
// MODE 1: out bf16, +bias, ReLU      (FFN1)
// MODE 2: out f32,  +bias            (FFN2)
template <int MODE>
__global__ __launch_bounds__(256) void gemm_bt(const short* __restrict__ A,
                                               const short* __restrict__ Bt,
                                               void* __restrict__ Cv,
                                               const float* __restrict__ bias,
                                               int M, int N, int K,
                                               long sA, long sB, long sC, long sBias) {
    __shared__ short As[128 * 32];
    __shared__ short Bs[128 * 32];
    const int tid = threadIdx.x;
    const int lane = tid & 63, w = tid >> 6;
    const long z = blockIdx.z;
    A += z * sA; Bt += z * sB; bias += z * sBias;
    const long brow = (long)blockIdx.y * 128, bcol = (long)blockIdx.x * 128;

    const int srow = w * 32 + (lane >> 2);   // staged row for inst 0 (inst1: +16)
    const int koff = (lane & 3) * 8;
    const short* ga0 = A  + (brow + srow) * (long)K + koff;
    const short* ga1 = ga0 + 16L * K;
    const short* gb0 = Bt + (bcol + srow) * (long)K + koff;
    const short* gb1 = gb0 + 16L * K;
    short* lA0 = As + (w * 2 + 0) * 512;   // 512 shorts = 1024B per wave-inst
    short* lA1 = As + (w * 2 + 1) * 512;
    short* lB0 = Bs + (w * 2 + 0) * 512;
    short* lB1 = Bs + (w * 2 + 1) * 512;

    const int wr = w >> 1, wc = w & 1;
    const int fr = lane & 15, fq = lane >> 4;
    f32x4 acc[4][4] = {};

    for (int k0 = 0; k0 < K; k0 += 32) {
        gld_lds16(ga0, lA0); gld_lds16(ga1, lA1);
        gld_lds16(gb0, lB0); gld_lds16(gb1, lB1);
        ga0 += 32; ga1 += 32; gb0 += 32; gb1 += 32;
        __syncthreads();
        short8 af[4], bf[4];
#pragma unroll
        for (int m = 0; m < 4; m++)
            af[m] = *(const short8*)(As + (wr * 64 + m * 16 + fr) * 32 + fq * 8);
#pragma unroll
        for (int n = 0; n < 4; n++)
            bf[n] = *(const short8*)(Bs + (wc * 64 + n * 16 + fr) * 32 + fq * 8);
#pragma unroll
        for (int m = 0; m < 4; m++)
#pragma unroll
            for (int n = 0; n < 4; n++)
                acc[m][n] = __builtin_amdgcn_mfma_f32_16x16x32_bf16(af[m], bf[n], acc[m][n], 0, 0, 0);
        __syncthreads();
    }

    const long crow0 = brow + wr * 64, ccol0 = bcol + wc * 64;
#pragma unroll
    for (int n = 0; n < 4; n++) {
        long col = ccol0 + n * 16 + fr;
        float bv = bias[col];
#pragma unroll
        for (int m = 0; m < 4; m++) {
#pragma unroll
            for (int r = 0; r < 4; r++) {
                long row = crow0 + m * 16 + fq * 4 + r;
                float v = acc[m][n][r] + bv;
                if (MODE == 1) v = fmaxf(v, 0.f);
                if (MODE == 2)
                    ((float*)Cv)[z * sC + row * (long)N + col] = v;
                else
                    ((short*)Cv)[z * sC + row * (long)N + col] = f2bf(v);
            }
        }
    }
}

// ---------------- flash attention: 1 wave = 16 q rows, KVBLK=64 -------------
// Q,K: [H][N][DK] bf16.  VT: [H][DK][N] bf16.  O: [N][DMODEL] f32.
__global__ __launch_bounds__(256) void attn_flash(const short* __restrict__ Q,
                                                  const short* __restrict__ Kc,
                                                  const short* __restrict__ VT,
                                                  float* __restrict__ O) {
    __shared__ short P[4][16 * 64];
    const int tid = threadIdx.x, lane = tid & 63, w = tid >> 6;
    const int wid = blockIdx.x * 4 + w;
    const int h = wid >> 7, qt = wid & 127;
    const int fr = lane & 15, fq = lane >> 4;
    const long qbase = (long)qt * 16;
    const short* Qh = Q  + (long)h * N_TOK * DK;
    const short* Kh = Kc + (long)h * N_TOK * DK;
    const short* Vh = VT + (long)h * DK * N_TOK;

    short8 qf[4];
#pragma unroll
    for (int c = 0; c < 4; c++)
        qf[c] = *(const short8*)(Qh + (qbase + fr) * DK + c * 32 + fq * 8);

    float mrow[4], lrow[4];
    f32x4 oacc[8] = {};
#pragma unroll
    for (int r = 0; r < 4; r++) { mrow[r] = -1e30f; lrow[r] = 0.f; }
    const float C1 = 0.08838834764831845f * 1.4426950408889634f; // 1/sqrt(128)*log2(e)
    short* Pw = P[w];

    for (int kv = 0; kv < N_TOK; kv += 64) {
        f32x4 s[4] = {};
#pragma unroll
        for (int jc = 0; jc < 4; jc++) {
#pragma unroll
            for (int c = 0; c < 4; c++) {
                short8 kf = *(const short8*)(Kh + (long)(kv + jc * 16 + fr) * DK + c * 32 + fq * 8);
                s[jc] = __builtin_amdgcn_mfma_f32_16x16x32_bf16(qf[c], kf, s[jc], 0, 0, 0);
            }
        }
        // online softmax (rows = fq*4+r, reduce over key-lanes fr)
        float resc[4];
#pragma unroll
        for (int r = 0; r < 4; r++) {
            float tm = fmaxf(fmaxf(s[0][r], s[1][r]), fmaxf(s[2][r], s[3][r]));
#pragma unroll
            for (int o = 1; o < 16; o <<= 1) tm = fmaxf(tm, __shfl_xor(tm, o));
            float nm = fmaxf(mrow[r], tm);
            resc[r] = exp2f(C1 * (mrow[r] - nm));
            mrow[r] = nm;
        }
#pragma unroll
        for (int r = 0; r < 4; r++) {
            float acc = 0.f;
#pragma unroll
            for (int jc = 0; jc < 4; jc++) {
                float p = exp2f(C1 * (s[jc][r] - mrow[r]));
                s[jc][r] = p;
                acc += p;
            }
#pragma unroll
            for (int o = 1; o < 16; o <<= 1) acc += __shfl_xor(acc, o);
            lrow[r] = lrow[r] * resc[r] + acc;
        }
#pragma unroll
        for (int f = 0; f < 8; f++)
#pragma unroll
            for (int r = 0; r < 4; r++) oacc[f][r] *= resc[r];
        // P -> LDS (per-wave region; same-wave ds ordering handled by lgkmcnt)
#pragma unroll
        for (int jc = 0; jc < 4; jc++)
#pragma unroll
            for (int r = 0; r < 4; r++)
                Pw[(fq * 4 + r) * 64 + jc * 16 + fr] = f2bf(s[jc][r]);
        short8 pa[2];
#pragma unroll
        for (int kc = 0; kc < 2; kc++)
            pa[kc] = *(const short8*)(Pw + fr * 64 + kc * 32 + fq * 8);
#pragma unroll
        for (int f = 0; f < 8; f++) {
#pragma unroll
            for (int kc = 0; kc < 2; kc++) {
                short8 vf = *(const short8*)(Vh + (f * 16 + fr) * (long)N_TOK + kv + kc * 32 + fq * 8);
                oacc[f] = __builtin_amdgcn_mfma_f32_16x16x32_bf16(pa[kc], vf, oacc[f], 0, 0, 0);
            }
        }
    }
#pragma unroll
    for (int r = 0; r < 4; r++) {
        float inv = 1.f / lrow[r];
        long row = qbase + fq * 4 + r;
#pragma unroll
        for (int f = 0; f < 8; f++)
            O[row * (long)DMODEL + h * DK + f * 16 + fr] = oacc[f][r] * inv;
    }
}

// ---------------- fused Add + LayerNorm (1 block = 1 row of 2048) -----------
template <bool WBF>
__global__ __launch_bounds__(256) void add_ln(const float* __restrict__ A,
                                              const float* __restrict__ B,
                                              const float* __restrict__ alpha,
                                              const float* __restrict__ beta,
                                              float* __restrict__ out,
                                              short* __restrict__ outbf) {
    const int row = blockIdx.x, t = threadIdx.x;
    const long base = (long)row * DMODEL;
    float4 va[2], vb[2];
    float s = 0.f, q = 0.f;
#pragma unroll
    for (int i = 0; i < 2; i++) {
        long off = base + (long)(t + i * 256) * 4;
        va[i] = *(const float4*)(A + off);
        vb[i] = *(const float4*)(B + off);
        float x0 = va[i].x + vb[i].x, x1 = va[i].y + vb[i].y;
        float x2 = va[i].z + vb[i].z, x3 = va[i].w + vb[i].w;
        s += x0 + x1 + x2 + x3;
        q += x0 * x0 + x1 * x1 + x2 * x2 + x3 * x3;
    }
#pragma unroll
    for (int o = 1; o < 64; o <<= 1) { s += __shfl_xor(s, o); q += __shfl_xor(q, o); }
    __shared__ float red[8];
    if ((t & 63) == 0) { red[t >> 6] = s; red[4 + (t >> 6)] = q; }
    __syncthreads();
    s = red[0] + red[1] + red[2] + red[3];
    q = red[4] + red[5] + red[6] + red[7];
    const float mean = s * (1.f / DMODEL);
    const float var = q * (1.f / DMODEL) - mean * mean;
    const float rstd = rsqrtf(var + 1e-5f);
#pragma unroll
    for (int i = 0; i < 2; i++) {
        long off = base + (long)(t + i * 256) * 4;
        float4 al = *(const float4*)(alpha + off);
        float4 be = *(const float4*)(beta + off);
        float x[4] = { va[i].x + vb[i].x, va[i].y + vb[i].y, va[i].z + vb[i].z, va[i].w + vb[i].w };
        float a[4] = { al.x, al.y, al.z, al.w };
        float b[4] = { be.x, be.y, be.z, be.w };
#pragma unroll
        for (int j = 0; j < 4; j++) {
            float o2 = (x[j] - mean) * rstd * a[j] + b[j];
            out[off + j] = o2;
            if (WBF) outbf[off + j] = f2bf(o2);
        }
    }
}

extern "C" void kernel_launch(void* const* d_in, const int* in_sizes, int n_in,
                              void* d_out, int out_size, void* d_ws, size_t ws_size,
                              hipStream_t stream) {
    const float* X      = (const float*)d_in[0];
    const float* Wq     = (const float*)d_in[1];
    const float* bq     = (const float*)d_in[2];
    const float* Wk     = (const float*)d_in[3];
    const float* bk     = (const float*)d_in[4];
    const float* Wv     = (const float*)d_in[5];
    const float* bv     = (const float*)d_in[6];
    const float* alpha1 = (const float*)d_in[7];
    const float* beta1  = (const float*)d_in[8];
    const float* W1     = (const float*)d_in[9];
    const float* b1     = (const float*)d_in[10];
    const float* W2     = (const float*)d_in[11];
    const float* b2     = (const float*)d_in[12];
    const float* alpha2 = (const float*)d_in[13];
    const float* beta2  = (const float*)d_in[14];
    float* out = (float*)d_out;

    char* ws = (char*)d_ws;
    size_t off = 0;
    auto alloc = [&](size_t bytes) -> void* {
        void* p = ws + off;
        off += (bytes + 255) & ~(size_t)255;
        return p;
    };
    short* XBF   = (short*)alloc(2048UL * 2048 * 2);       // X bf16
    short* WQKVT = (short*)alloc(48UL * 128 * 2048 * 2);   // Wq/Wk/Wv^T bf16 (48 slabs of [128][2048])
    short* W1T   = (short*)alloc(8192UL * 2048 * 2);       // W1^T bf16 [8192][2048]
    short* W2T   = (short*)alloc(2048UL * 8192 * 2);       // W2^T bf16 [2048][8192]
    short* QKV   = (short*)alloc(48UL * 2048 * 128 * 2);   // Q(0-15),K(16-31),V(32-47) slabs [2048][128]
    short* VT    = (short*)alloc(16UL * 128 * 2048 * 2);   // V^T per head [128][2048]
    float* ATTN  = (float*)alloc(2048UL * 2048 * 4);
    float* H1    = (float*)alloc(2048UL * 2048 * 4);
    short* H1BF  = (short*)alloc(2048UL * 2048 * 2);
    short* G     = (short*)alloc(2048UL * 8192 * 2);       // relu(h1 W1 + b1) bf16
    float* F     = (float*)alloc(2048UL * 2048 * 4);

    // 1. casts / transposes
    cast_f32_bf16<<<2048, 256, 0, stream>>>(X, XBF, 2048 * 2048 / 8);
    transpose_cast<float><<<dim3(2, 32, 16), 256, 0, stream>>>(Wq, WQKVT,               2048, 128, 2048L * 128, 128L * 2048);
    transpose_cast<float><<<dim3(2, 32, 16), 256, 0, stream>>>(Wk, WQKVT + 16L * 128 * 2048, 2048, 128, 2048L * 128, 128L * 2048);
    transpose_cast<float><<<dim3(2, 32, 16), 256, 0, stream>>>(Wv, WQKVT + 32L * 128 * 2048, 2048, 128, 2048L * 128, 128L * 2048);
    transpose_cast<float><<<dim3(128, 32, 1), 256, 0, stream>>>(W1, W1T, 2048, 8192, 0, 0);
    transpose_cast<float><<<dim3(32, 128, 1), 256, 0, stream>>>(W2, W2T, 8192, 2048, 0, 0);

    // 2. QKV projections (batched over heads)
    gemm_bt<0><<<dim3(1, 16, 16), 256, 0, stream>>>(XBF, WQKVT,                QKV,                    bq, 2048, 128, 2048, 0, 128L * 2048, 2048L * 128, 128);
    gemm_bt<0><<<dim3(1, 16, 16), 256, 0, stream>>>(XBF, WQKVT + 16L * 128 * 2048, QKV + 16L * 2048 * 128, bk, 2048, 128, 2048, 0, 128L * 2048, 2048L * 128, 128);
    gemm_bt<0><<<dim3(1, 16, 16), 256, 0, stream>>>(XBF, WQKVT + 32L * 128 * 2048, QKV + 32L * 2048 * 128, bv, 2048, 128, 2048, 0, 128L * 2048, 2048L * 128, 128);

    // 3. V -> V^T per head
    transpose_cast<__hip_bfloat16><<<dim3(2, 32, 16), 256, 0, stream>>>(
        (const __hip_bfloat16*)(QKV + 32L * 2048 * 128), VT, 2048, 128, 2048L * 128, 128L * 2048);

    // 4. attention
    attn_flash<<<512, 256, 0, stream>>>(QKV, QKV + 16L * 2048 * 128, VT, ATTN);

    // 5. Add & LN 1 (writes f32 + bf16)
    add_ln<true><<<2048, 256, 0, stream>>>(X, ATTN, alpha1, beta1, H1, H1BF);

    // 6. FFN
    gemm_bt<1><<<dim3(64, 16, 1), 256, 0, stream>>>(H1BF, W1T, G, b1, 2048, 8192, 2048, 0, 0, 0, 0);
    gemm_bt<2><<<dim3(16, 16, 1), 256, 0, stream>>>(G, W2T, F, b2, 2048, 2048, 8192, 0, 0, 0, 0);

    // 7. Add & LN 2 -> output
    add_ln<false><<<2048, 256, 0, stream>>>(H1, F, alpha2, beta2, out, nullptr);
}

// Round 2
// 563.978 us; speedup vs baseline: 1.4700x; 1.4700x over previous
//
#include <hip/hip_runtime.h>
#include <hip/hip_bf16.h>

#define N_TOK 2048
#define DMODEL 2048
#define NH 16
#define DK 128
#define DFF 8192

typedef __attribute__((ext_vector_type(8))) short short8;
typedef __attribute__((ext_vector_type(4))) short s16x4;
typedef __attribute__((ext_vector_type(4))) float f32x4;

__device__ __forceinline__ short f2bf(float f) {
    unsigned int x = __builtin_bit_cast(unsigned int, f);
    unsigned int r = (x + 0x7fffu + ((x >> 16) & 1u)) >> 16;
    return (short)r;
}

// ---------------- cast X (f32 -> bf16), 8 elems/thread ----------------
__global__ __launch_bounds__(256) void cast_f32_bf16(const float* __restrict__ in,
                                                     short* __restrict__ out, int n8) {
    int i = blockIdx.x * 256 + threadIdx.x;
    if (i >= n8) return;
    const float4* p = (const float4*)in + (size_t)i * 2;
    float4 a = p[0], b = p[1];
    short8 o;
    o[0] = f2bf(a.x); o[1] = f2bf(a.y); o[2] = f2bf(a.z); o[3] = f2bf(a.w);
    o[4] = f2bf(b.x); o[5] = f2bf(b.y); o[6] = f2bf(b.z); o[7] = f2bf(b.w);
    *(short8*)(out + (size_t)i * 8) = o;
}

// ---------------- transpose + cast to bf16 (64x64 LDS tiles) ----------------
template <typename TIN>
__global__ __launch_bounds__(256) void transpose_cast(const TIN* __restrict__ in,
                                                      short* __restrict__ out,
                                                      int R, int C, long sIn, long sOut) {
    __shared__ float t[64][65];
    in  += (long)blockIdx.z * sIn;
    out += (long)blockIdx.z * sOut;
    int tx = threadIdx.x & 63, ty = threadIdx.x >> 6;
    long r0 = (long)blockIdx.y * 64, c0 = (long)blockIdx.x * 64;
    for (int i = 0; i < 16; i++) {
        int r = ty + i * 4;
        t[r][tx] = (float)in[(r0 + r) * (long)C + c0 + tx];
    }
    __syncthreads();
    for (int i = 0; i < 16; i++) {
        int r = ty + i * 4;
        out[(c0 + r) * (long)R + r0 + tx] = f2bf(t[tx][r]);
    }
}

// ---------------- async global->LDS helper ----------------
__device__ __forceinline__ void gld_lds16(const short* g, short* l) {
    __builtin_amdgcn_global_load_lds(
        (const __attribute__((address_space(1))) void*)g,
        (__attribute__((address_space(3))) void*)l, 16, 0, 0);
}

// ---------------- bf16 GEMM, B pre-transposed ([n][k]) -------------------
// 128x128 tile, 4 waves (2x2 of 64x64), BK=32, m97 structure.
// MODE 0: out bf16, +bias (QKV batched z=48, bias selected by z>>4)
// MODE 1: out bf16, +bias, ReLU      (FFN1)
// MODE 3: out f32, no bias, split-K slab z  (FFN2)
template <int MODE>
__global__ __launch_bounds__(256) void gemm_bt(const short* __restrict__ A,
                                               const short* __restrict__ Bt,
                                               void* __restrict__ Cv,
                                               const float* __restrict__ bias,
                                               const float* __restrict__ bias2,
                                               const float* __restrict__ bias3,
                                               int M, int N, int K, int Kloop,
                                               long sA, long sB, long sC) {
    __shared__ short As[128 * 32];
    __shared__ short Bs[128 * 32];
    const int tid = threadIdx.x;
    const int lane = tid & 63, w = tid >> 6;
    const long z = blockIdx.z;
    const float* bp = bias;
    if (MODE == 0) {
        int sel = (int)(z >> 4);
        bp = (sel == 0 ? bias : sel == 1 ? bias2 : bias3) + (z & 15) * 128;
        Bt += z * sB;
    } else if (MODE == 3) {
        A += z * (long)Kloop;
        Bt += z * (long)Kloop;
    } else {
        A += z * sA; Bt += z * sB;
    }
    const long brow = (long)blockIdx.y * 128, bcol = (long)blockIdx.x * 128;

    const int srow = w * 32 + (lane >> 2);
    const int koff = (lane & 3) * 8;
    const short* ga0 = A  + (brow + srow) * (long)K + koff;
    const short* ga1 = ga0 + 16L * K;
    const short* gb0 = Bt + (bcol + srow) * (long)K + koff;
    const short* gb1 = gb0 + 16L * K;
    short* lA0 = As + (w * 2 + 0) * 512;
    short* lA1 = As + (w * 2 + 1) * 512;
    short* lB0 = Bs + (w * 2 + 0) * 512;
    short* lB1 = Bs + (w * 2 + 1) * 512;

    const int wr = w >> 1, wc = w & 1;
    const int fr = lane & 15, fq = lane >> 4;
    f32x4 acc[4][4] = {};

    for (int k0 = 0; k0 < Kloop; k0 += 32) {
        gld_lds16(ga0, lA0); gld_lds16(ga1, lA1);
        gld_lds16(gb0, lB0); gld_lds16(gb1, lB1);
        ga0 += 32; ga1 += 32; gb0 += 32; gb1 += 32;
        __syncthreads();
        short8 af[4], bf[4];
#pragma unroll
        for (int m = 0; m < 4; m++)
            af[m] = *(const short8*)(As + (wr * 64 + m * 16 + fr) * 32 + fq * 8);
#pragma unroll
        for (int n = 0; n < 4; n++)
            bf[n] = *(const short8*)(Bs + (wc * 64 + n * 16 + fr) * 32 + fq * 8);
#pragma unroll
        for (int m = 0; m < 4; m++)
#pragma unroll
            for (int n = 0; n < 4; n++)
                acc[m][n] = __builtin_amdgcn_mfma_f32_16x16x32_bf16(af[m], bf[n], acc[m][n], 0, 0, 0);
        __syncthreads();
    }

    const long crow0 = brow + wr * 64, ccol0 = bcol + wc * 64;
#pragma unroll
    for (int n = 0; n < 4; n++) {
        long col = ccol0 + n * 16 + fr;
        float bv = (MODE == 3) ? 0.f : bp[col];
#pragma unroll
        for (int m = 0; m < 4; m++) {
#pragma unroll
            for (int r = 0; r < 4; r++) {
                long row = crow0 + m * 16 + fq * 4 + r;
                float v = acc[m][n][r] + bv;
                if (MODE == 1) v = fmaxf(v, 0.f);
                if (MODE == 3)
                    ((float*)Cv)[z * sC + row * (long)N + col] = v;
                else
                    ((short*)Cv)[z * sC + row * (long)N + col] = f2bf(v);
            }
        }
    }
}

// ---------------- flash attention v2: swapped QK^T, 32 q-rows/wave ----------
// Q,K: [H][N][DK] bf16.  VT: [H][DK][N] bf16.  O: [N][DMODEL] f32.
// Per wave: 2 groups of 16 q-rows; lane holds full q-row (q=fr) scores.
__global__ __launch_bounds__(256, 1) void attn_flash(const short* __restrict__ Q,
                                                     const short* __restrict__ Kc,
                                                     const short* __restrict__ VT,
                                                     float* __restrict__ O) {
    __shared__ short P[4][2][16 * 64];  // [wave][group], XOR-swizzled rows
    const int tid = threadIdx.x, lane = tid & 63, w = tid >> 6;
    const int h = blockIdx.x >> 4, qt = blockIdx.x & 15;
    const int fr = lane & 15, fq = lane >> 4;
    const long qbase = (long)qt * 128 + w * 32;
    const short* Qh = Q  + (long)h * N_TOK * DK;
    const short* Kh = Kc + (long)h * N_TOK * DK;
    const short* Vh = VT + (long)h * DK * N_TOK;

    // Q fragments (B-operand of swapped QK): lane holds Q[qbase+g*16+fr][k-chunk]
    short8 qf[2][4];
#pragma unroll
    for (int g = 0; g < 2; g++)
#pragma unroll
        for (int c = 0; c < 4; c++)
            qf[g][c] = *(const short8*)(Qh + (qbase + g * 16 + fr) * DK + c * 32 + fq * 8);

    float mrow[2] = {-1e30f, -1e30f}, lrow[2] = {0.f, 0.f};
    f32x4 oacc[2][8] = {};
    const float C1 = 0.08838834764831845f * 1.4426950408889634f; // 1/sqrt(128)*log2e

    // swizzled LDS offsets (in shorts); same involution on write & read
    int wr_off[4], rd_off[2];
#pragma unroll
    for (int jc = 0; jc < 4; jc++)
        wr_off[jc] = (fr * 64 + jc * 16 + fq * 4) ^ ((fr & 7) << 3);
#pragma unroll
    for (int kc = 0; kc < 2; kc++)
        rd_off[kc] = (fr * 64 + kc * 32 + fq * 8) ^ ((fr & 7) << 3);

    for (int kv = 0; kv < N_TOK; kv += 64) {
        // K fragments (A-operand): lane holds K[kv+jc*16+fr][k-chunk]
        short8 kf[16];
#pragma unroll
        for (int jc = 0; jc < 4; jc++)
#pragma unroll
            for (int c = 0; c < 4; c++)
                kf[jc * 4 + c] = *(const short8*)(Kh + (long)(kv + jc * 16 + fr) * DK + c * 32 + fq * 8);

        // S^T = K . Q^T : lane holds S[key=jc*16+fq*4+r][q=fr]
        f32x4 s[2][4] = {};
#pragma unroll
        for (int g = 0; g < 2; g++)
#pragma unroll
            for (int jc = 0; jc < 4; jc++)
#pragma unroll
                for (int c = 0; c < 4; c++)
                    s[g][jc] = __builtin_amdgcn_mfma_f32_16x16x32_bf16(kf[jc * 4 + c], qf[g][c], s[g][jc], 0, 0, 0);

        // online softmax: per-lane row (q=fr) of 16 keys; reduce across fq lanes
#pragma unroll
        for (int g = 0; g < 2; g++) {
            float tm = -1e30f;
#pragma unroll
            for (int jc = 0; jc < 4; jc++)
#pragma unroll
                for (int r = 0; r < 4; r++) tm = fmaxf(tm, s[g][jc][r]);
            tm = fmaxf(tm, __shfl_xor(tm, 16));
            tm = fmaxf(tm, __shfl_xor(tm, 32));
            float nm = fmaxf(mrow[g], tm);
            float resc = exp2f(C1 * (mrow[g] - nm));
            mrow[g] = nm;
            float sum = 0.f;
#pragma unroll
            for (int jc = 0; jc < 4; jc++)
#pragma unroll
                for (int r = 0; r < 4; r++) {
                    float p = exp2f(C1 * (s[g][jc][r] - nm));
                    s[g][jc][r] = p;
                    sum += p;
                }
            sum += __shfl_xor(sum, 16);
            sum += __shfl_xor(sum, 32);
            lrow[g] = lrow[g] * resc + sum;
#pragma unroll
            for (int f = 0; f < 8; f++)
#pragma unroll
                for (int r = 0; r < 4; r++) oacc[g][f][r] *= resc;
            // P row (q=fr, keys jc*16+fq*4+0..3) packed b64, swizzled
            short* Pg = P[w][g];
#pragma unroll
            for (int jc = 0; jc < 4; jc++) {
                s16x4 pk;
                pk[0] = f2bf(s[g][jc][0]); pk[1] = f2bf(s[g][jc][1]);
                pk[2] = f2bf(s[g][jc][2]); pk[3] = f2bf(s[g][jc][3]);
                *(s16x4*)(Pg + wr_off[jc]) = pk;
            }
        }
        // P fragments (B-operand of PV): lane holds P[q=fr][kc*32+fq*8..+7]
        short8 pa[2][2];
#pragma unroll
        for (int g = 0; g < 2; g++)
#pragma unroll
            for (int kc = 0; kc < 2; kc++)
                pa[g][kc] = *(const short8*)(P[w][g] + rd_off[kc]);
        // O^T += V^T . P^T : A-frag = VT rows (d=f*16+fr), D row=d, col=q=fr
#pragma unroll
        for (int f = 0; f < 8; f++) {
#pragma unroll
            for (int kc = 0; kc < 2; kc++) {
                short8 vf = *(const short8*)(Vh + (f * 16 + fr) * (long)N_TOK + kv + kc * 32 + fq * 8);
#pragma unroll
                for (int g = 0; g < 2; g++)
                    oacc[g][f] = __builtin_amdgcn_mfma_f32_16x16x32_bf16(vf, pa[g][kc], oacc[g][f], 0, 0, 0);
            }
        }
    }
#pragma unroll
    for (int g = 0; g < 2; g++) {
        float inv = 1.f / lrow[g];
        long row = qbase + g * 16 + fr;
#pragma unroll
        for (int f = 0; f < 8; f++) {
            float4 o;
            o.x = oacc[g][f][0] * inv; o.y = oacc[g][f][1] * inv;
            o.z = oacc[g][f][2] * inv; o.w = oacc[g][f][3] * inv;
            *(float4*)(O + row * (long)DMODEL + h * DK + f * 16 + fq * 4) = o;
        }
    }
}

// ---------------- fused Add + LayerNorm (1 block = 1 row of 2048) -----------
template <bool WBF>
__global__ __launch_bounds__(256) void add_ln(const float* __restrict__ A,
                                              const float* __restrict__ B,
                                              const float* __restrict__ alpha,
                                              const float* __restrict__ beta,
                                              float* __restrict__ out,
                                              short* __restrict__ outbf) {
    const int row = blockIdx.x, t = threadIdx.x;
    const long base = (long)row * DMODEL;
    float4 va[2], vb[2];
    float s = 0.f, q = 0.f;
#pragma unroll
    for (int i = 0; i < 2; i++) {
        long off = base + (long)(t + i * 256) * 4;
        va[i] = *(const float4*)(A + off);
        vb[i] = *(const float4*)(B + off);
        float x0 = va[i].x + vb[i].x, x1 = va[i].y + vb[i].y;
        float x2 = va[i].z + vb[i].z, x3 = va[i].w + vb[i].w;
        s += x0 + x1 + x2 + x3;
        q += x0 * x0 + x1 * x1 + x2 * x2 + x3 * x3;
    }
#pragma unroll
    for (int o = 1; o < 64; o <<= 1) { s += __shfl_xor(s, o); q += __shfl_xor(q, o); }
    __shared__ float red[8];
    if ((t & 63) == 0) { red[t >> 6] = s; red[4 + (t >> 6)] = q; }
    __syncthreads();
    s = red[0] + red[1] + red[2] + red[3];
    q = red[4] + red[5] + red[6] + red[7];
    const float mean = s * (1.f / DMODEL);
    const float var = q * (1.f / DMODEL) - mean * mean;
    const float rstd = rsqrtf(var + 1e-5f);
#pragma unroll
    for (int i = 0; i < 2; i++) {
        long off = base + (long)(t + i * 256) * 4;
        float4 al = *(const float4*)(alpha + off);
        float4 be = *(const float4*)(beta + off);
        float x[4] = { va[i].x + vb[i].x, va[i].y + vb[i].y, va[i].z + vb[i].z, va[i].w + vb[i].w };
        float a[4] = { al.x, al.y, al.z, al.w };
        float b[4] = { be.x, be.y, be.z, be.w };
#pragma unroll
        for (int j = 0; j < 4; j++) {
            float o2 = (x[j] - mean) * rstd * a[j] + b[j];
            out[off + j] = o2;
            if (WBF) outbf[off + j] = f2bf(o2);
        }
    }
}

// ---------------- Add + LN2 with 4-slab split-K reduction + bias ------------
__global__ __launch_bounds__(256) void add_ln2_red(const float* __restrict__ H1,
                                                   const float* __restrict__ F4,
                                                   const float* __restrict__ b2,
                                                   const float* __restrict__ alpha,
                                                   const float* __restrict__ beta,
                                                   float* __restrict__ out) {
    const int row = blockIdx.x, t = threadIdx.x;
    const long base = (long)row * DMODEL;
    const long SL = (long)N_TOK * DMODEL;
    float x[8];
    float s = 0.f, q = 0.f;
#pragma unroll
    for (int i = 0; i < 2; i++) {
        long off = base + (long)(t + i * 256) * 4;
        int col = (t + i * 256) * 4;
        float4 a  = *(const float4*)(H1 + off);
        float4 f0 = *(const float4*)(F4 + off);
        float4 f1 = *(const float4*)(F4 + off + SL);
        float4 f2 = *(const float4*)(F4 + off + 2 * SL);
        float4 f3 = *(const float4*)(F4 + off + 3 * SL);
        float4 bb = *(const float4*)(b2 + col);
        x[i * 4 + 0] = a.x + f0.x + f1.x + f2.x + f3.x + bb.x;
        x[i * 4 + 1] = a.y + f0.y + f1.y + f2.y + f3.y + bb.y;
        x[i * 4 + 2] = a.z + f0.z + f1.z + f2.z + f3.z + bb.z;
        x[i * 4 + 3] = a.w + f0.w + f1.w + f2.w + f3.w + bb.w;
#pragma unroll
        for (int j = 0; j < 4; j++) { s += x[i * 4 + j]; q += x[i * 4 + j] * x[i * 4 + j]; }
    }
#pragma unroll
    for (int o = 1; o < 64; o <<= 1) { s += __shfl_xor(s, o); q += __shfl_xor(q, o); }
    __shared__ float red[8];
    if ((t & 63) == 0) { red[t >> 6] = s; red[4 + (t >> 6)] = q; }
    __syncthreads();
    s = red[0] + red[1] + red[2] + red[3];
    q = red[4] + red[5] + red[6] + red[7];
    const float mean = s * (1.f / DMODEL);
    const float var = q * (1.f / DMODEL) - mean * mean;
    const float rstd = rsqrtf(var + 1e-5f);
#pragma unroll
    for (int i = 0; i < 2; i++) {
        long off = base + (long)(t + i * 256) * 4;
        float4 al = *(const float4*)(alpha + off);
        float4 be = *(const float4*)(beta + off);
        float a[4] = { al.x, al.y, al.z, al.w };
        float b[4] = { be.x, be.y, be.z, be.w };
#pragma unroll
        for (int j = 0; j < 4; j++)
            out[off + j] = (x[i * 4 + j] - mean) * rstd * a[j] + b[j];
    }
}

extern "C" void kernel_launch(void* const* d_in, const int* in_sizes, int n_in,
                              void* d_out, int out_size, void* d_ws, size_t ws_size,
                              hipStream_t stream) {
    const float* X      = (const float*)d_in[0];
    const float* Wq     = (const float*)d_in[1];
    const float* bq     = (const float*)d_in[2];
    const float* Wk     = (const float*)d_in[3];
    const float* bk     = (const float*)d_in[4];
    const float* Wv     = (const float*)d_in[5];
    const float* bv     = (const float*)d_in[6];
    const float* alpha1 = (const float*)d_in[7];
    const float* beta1  = (const float*)d_in[8];
    const float* W1     = (const float*)d_in[9];
    const float* b1     = (const float*)d_in[10];
    const float* W2     = (const float*)d_in[11];
    const float* b2     = (const float*)d_in[12];
    const float* alpha2 = (const float*)d_in[13];
    const float* beta2  = (const float*)d_in[14];
    float* out = (float*)d_out;

    char* ws = (char*)d_ws;
    size_t off = 0;
    auto alloc = [&](size_t bytes) -> void* {
        void* p = ws + off;
        off += (bytes + 255) & ~(size_t)255;
        return p;
    };
    short* XBF   = (short*)alloc(2048UL * 2048 * 2);       // freed after QKV gemm
    short* WQKVT = (short*)alloc(48UL * 128 * 2048 * 2);   // freed after QKV gemm
    short* W1T   = (short*)alloc(8192UL * 2048 * 2);       // freed after FFN1
    short* W2T   = (short*)alloc(2048UL * 8192 * 2);
    short* QKV   = (short*)alloc(48UL * 2048 * 128 * 2);   // Q(0-15),K(16-31),V(32-47)
    short* VT    = (short*)alloc(16UL * 128 * 2048 * 2);
    float* ATTN  = (float*)alloc(2048UL * 2048 * 4);
    float* H1    = (float*)alloc(2048UL * 2048 * 4);
    short* H1BF  = (short*)alloc(2048UL * 2048 * 2);
    short* G     = (short*)alloc(2048UL * 8192 * 2);
    // F4 (64 MB, 4 split-K slabs) aliases XBF+WQKVT+W1T (67 MB), all dead by FFN2
    float* F4 = (float*)XBF;

    // 1. casts / transposes
    cast_f32_bf16<<<2048, 256, 0, stream>>>(X, XBF, 2048 * 2048 / 8);
    transpose_cast<float><<<dim3(2, 32, 16), 256, 0, stream>>>(Wq, WQKVT,                    2048, 128, 2048L * 128, 128L * 2048);
    transpose_cast<float><<<dim3(2, 32, 16), 256, 0, stream>>>(Wk, WQKVT + 16L * 128 * 2048, 2048, 128, 2048L * 128, 128L * 2048);
    transpose_cast<float><<<dim3(2, 32, 16), 256, 0, stream>>>(Wv, WQKVT + 32L * 128 * 2048, 2048, 128, 2048L * 128, 128L * 2048);
    transpose_cast<float><<<dim3(128, 32, 1), 256, 0, stream>>>(W1, W1T, 2048, 8192, 0, 0);
    transpose_cast<float><<<dim3(32, 128, 1), 256, 0, stream>>>(W2, W2T, 8192, 2048, 0, 0);

    // 2. QKV projections: single batched launch, z=48 (3 blocks/CU co-resident)
    gemm_bt<0><<<dim3(1, 16, 48), 256, 0, stream>>>(XBF, WQKVT, QKV, bq, bk, bv,
                                                    2048, 128, 2048, 2048, 0, 128L * 2048, 2048L * 128);

    // 3. V -> V^T per head
    transpose_cast<__hip_bfloat16><<<dim3(2, 32, 16), 256, 0, stream>>>(
        (const __hip_bfloat16*)(QKV + 32L * 2048 * 128), VT, 2048, 128, 2048L * 128, 128L * 2048);

    // 4. attention (256 blocks x 4 waves, 32 q-rows/wave)
    attn_flash<<<256, 256, 0, stream>>>(QKV, QKV + 16L * 2048 * 128, VT, ATTN);

    // 5. Add & LN 1
    add_ln<true><<<2048, 256, 0, stream>>>(X, ATTN, alpha1, beta1, H1, H1BF);

    // 6. FFN (FFN2 split-K=4 for co-residency)
    gemm_bt<1><<<dim3(64, 16, 1), 256, 0, stream>>>(H1BF, W1T, G, b1, nullptr, nullptr,
                                                    2048, 8192, 2048, 2048, 0, 0, 0);
    gemm_bt<3><<<dim3(16, 16, 4), 256, 0, stream>>>(G, W2T, F4, nullptr, nullptr, nullptr,
                                                    2048, 2048, 8192, 2048, 0, 0, 2048L * 2048);

    // 7. Add + reduce + LN 2 -> output
    add_ln2_red<<<2048, 256, 0, stream>>>(H1, F4, b2, alpha2, beta2, out);
}